// Round 1
// baseline (289.599 us; speedup 1.0000x reference)
//
#include <hip/hip_runtime.h>

// EMA recurrence: out[b,d,t] = a*x[b,d,t] + (1-a)*out[b,d,t-1], h_{-1} = hidden[b,d].
// Layout: [B=8, D=1024, T=4096] fp32, T contiguous. 8192 independent sequences.
//
// Parallelization: decay truncation. (1-a)^32 = 0.6^32 ~ 8e-8, so each thread
// independently computes C=128 contiguous outputs after a W=32 warm-up scan
// starting from h=0 (chunk 0 uses the true hidden init). Error ~2e-7 absolute,
// threshold 5.5e-2. Read amplification (C+W)/C = 1.25x; all loads/stores are
// aligned float4 (chunk bases are multiples of 128 floats = 512 B).

constexpr float ALPHA = 0.4f;
constexpr int   T_LEN = 4096;
constexpr int   C     = 128;          // outputs per thread
constexpr int   W     = 32;           // warm-up elements (0.6^32 ~ 8e-8)
constexpr int   CHUNKS_PER_SEQ = T_LEN / C;   // 32

__global__ __launch_bounds__(256) void ema_chunked_kernel(
    const float* __restrict__ x,
    const float* __restrict__ h0,
    float* __restrict__ out,
    int nseq)
{
    const int tid  = blockIdx.x * blockDim.x + threadIdx.x;
    const int seq  = tid / CHUNKS_PER_SEQ;
    const int cidx = tid % CHUNKS_PER_SEQ;
    if (seq >= nseq) return;

    const float a = ALPHA;
    const float b = 1.0f - ALPHA;

    const int base = seq * T_LEN + cidx * C;

    float h;
    if (cidx == 0) {
        h = h0[seq];
    } else {
        // Warm-up: scan the preceding W elements from h=0. Contribution of the
        // true state W steps back is attenuated by (1-a)^W ~ 8e-8 -> negligible.
        h = 0.0f;
        const float4* wp = (const float4*)(x + base - W);
        #pragma unroll
        for (int j = 0; j < W / 4; ++j) {
            float4 v = wp[j];
            // a*v off the critical path; dependent chain is one fma per element.
            h = fmaf(b, h, a * v.x);
            h = fmaf(b, h, a * v.y);
            h = fmaf(b, h, a * v.z);
            h = fmaf(b, h, a * v.w);
        }
    }

    const float4* xp = (const float4*)(x + base);
    float4*       op = (float4*)(out + base);
    #pragma unroll 4
    for (int j = 0; j < C / 4; ++j) {
        float4 v = xp[j];
        float4 o;
        h = fmaf(b, h, a * v.x); o.x = h;
        h = fmaf(b, h, a * v.y); o.y = h;
        h = fmaf(b, h, a * v.z); o.z = h;
        h = fmaf(b, h, a * v.w); o.w = h;
        op[j] = o;
    }
}

extern "C" void kernel_launch(void* const* d_in, const int* in_sizes, int n_in,
                              void* d_out, int out_size, void* d_ws, size_t ws_size,
                              hipStream_t stream) {
    const float* x  = (const float*)d_in[0];   // [8,1024,4096] fp32
    const float* h0 = (const float*)d_in[1];   // [8,1024,1]    fp32
    float* out = (float*)d_out;                // [8,1024,4096] fp32

    const int nseq = in_sizes[1];              // 8192 sequences
    const int total_threads = nseq * CHUNKS_PER_SEQ;  // 262144
    const int block = 256;
    const int grid = (total_threads + block - 1) / block;

    ema_chunked_kernel<<<grid, block, 0, stream>>>(x, h0, out, nseq);
}

// Round 2
// 232.657 us; speedup vs baseline: 1.2447x; 1.2447x over previous
//
#include <hip/hip_runtime.h>

// EMA recurrence: out[t] = a*x[t] + (1-a)*out[t-1] over T=4096 (contiguous),
// 8192 independent sequences [B=8, D=1024, T=4096] fp32.
//
// R2 design: fully-coalesced wave scan.
//   - One wave per sequence (8192 waves, 32 waves/CU).
//   - Per tile of 256 floats: lane i loads float4 x[tile*256 + 4i] (coalesced,
//     16 fully-used lines per instruction, vs 64 scattered lines in R1).
//   - Lane-local serial scan of 4 elements, then Kogge-Stone across lanes on
//     the segment tails with per-step multipliers b^4, b^8, b^16. Decay
//     truncation: the next term (b^32 ~ 8.4e-8) is negligible vs the 5.5e-2
//     threshold, so 3 shuffle steps suffice.
//   - Tile-to-tile carry: broadcast lane 63's scanned tail (b^256 == 0 in
//     fp32, so older state is exactly dead).
//   - Exact single-pass traffic: 134 MB read + 134 MB write, no warm-up
//     re-reads.

constexpr int T_LEN = 4096;
constexpr int TILE  = 256;             // floats per wave-tile (64 lanes x 4)
constexpr int NT    = T_LEN / TILE;    // 16 tiles per sequence

__global__ __launch_bounds__(256) void ema_wavescan_kernel(
    const float* __restrict__ x,
    const float* __restrict__ h0,
    float* __restrict__ out,
    int nseq)
{
    const int gtid = blockIdx.x * blockDim.x + threadIdx.x;
    const int wave = gtid >> 6;        // one wave per sequence
    const int lane = threadIdx.x & 63;
    if (wave >= nseq) return;

    const float a  = 0.4f;
    const float b  = 0.6f;
    const float b2 = b * b;
    const float b3 = b2 * b;
    const float b4 = b2 * b2;          // ratio between adjacent lane segments
    const float b8 = b4 * b4;
    const float b16 = b8 * b8;

    // b^(4*lane): scale for injecting the tile-incoming carry into lane i's
    // segment entry state. log2(0.6) = -0.736965594. Underflows to ~0 for
    // lane >~ 20, which is exactly the decay truncation we rely on.
    const float pb4i = exp2f((float)(4 * lane) * -0.736965594f);

    const float4* __restrict__ xp = (const float4*)(x + (size_t)wave * T_LEN);
    float4* __restrict__ op       = (float4*)(out + (size_t)wave * T_LEN);

    float h_in = h0[wave];             // true initial hidden state

    float4 v = xp[lane];               // prefetch tile 0
    #pragma unroll
    for (int it = 0; it < NT; ++it) {
        float4 vn;
        if (it + 1 < NT) vn = xp[(it + 1) * 64 + lane];  // prefetch next tile

        // Lane-local inclusive scan (zero-init): c_j = a*x_j + b*c_{j-1}
        float c0 = a * v.x;
        float c1 = fmaf(b, c0, a * v.y);
        float c2 = fmaf(b, c1, a * v.z);
        float c3 = fmaf(b, c2, a * v.w);

        // Kogge-Stone over lane tails; lane distance k carries weight b^(4k).
        // Steps beyond d=4 carry <= b^32 ~ 8.4e-8 -> dropped.
        float t = c3;
        float u;
        u = __shfl_up(t, 1, 64); t = fmaf(lane >= 1 ? b4  : 0.0f, u, t);
        u = __shfl_up(t, 2, 64); t = fmaf(lane >= 2 ? b8  : 0.0f, u, t);
        u = __shfl_up(t, 4, 64); t = fmaf(lane >= 4 ? b16 : 0.0f, u, t);

        // Exclusive scan value + incoming carry = h entering this lane's segment.
        u = __shfl_up(t, 1, 64);
        float e = fmaf(pb4i, h_in, lane == 0 ? 0.0f : u);

        // Final outputs: h_j = c_j + b^(j+1) * e
        float4 o;
        o.x = fmaf(b , e, c0);
        o.y = fmaf(b2, e, c1);
        o.z = fmaf(b3, e, c2);
        o.w = fmaf(b4, e, c3);
        op[it * 64 + lane] = o;

        // Carry for next tile: h at end of this tile (lane 63's scanned tail).
        h_in = __shfl(t, 63, 64);
        v = vn;
    }
}

extern "C" void kernel_launch(void* const* d_in, const int* in_sizes, int n_in,
                              void* d_out, int out_size, void* d_ws, size_t ws_size,
                              hipStream_t stream) {
    const float* x  = (const float*)d_in[0];   // [8,1024,4096] fp32
    const float* h0 = (const float*)d_in[1];   // [8,1024,1]    fp32
    float* out = (float*)d_out;                // [8,1024,4096] fp32

    const int nseq = in_sizes[1];              // 8192 sequences
    const int block = 256;                     // 4 waves -> 4 sequences/block
    const int grid = (nseq * 64 + block - 1) / block;  // 2048 blocks

    ema_wavescan_kernel<<<grid, block, 0, stream>>>(x, h0, out, nseq);
}

// Round 3
// 231.102 us; speedup vs baseline: 1.2531x; 1.0067x over previous
//
#include <hip/hip_runtime.h>

// EMA recurrence: out[t] = a*x[t] + (1-a)*out[t-1] over T=4096 (contiguous),
// 8192 independent sequences [B=8, D=1024, T=4096] fp32.
//
// R3: R2's coalesced wave-scan + deep memory pipelining.
//   - R2 post-mortem: VGPR=32, only 1-deep prefetch -> <=2 loads in flight
//     per wave -> latency-bound at 2.45 TB/s while fillBuffer hits 6.6 TB/s
//     at 9.7% occupancy in the same capture. The fix is MLP, not occupancy.
//   - Preload ALL 16 tiles (16 independent global_load_dwordx4, 64 VGPRs)
//     before the scan phase; consume in order with vmcnt(15..0)-style waits.
//   - 4 DS ops/tile instead of 5: exclusive tail recovered algebraically as
//     e = (t - c3) / b^4 (dropped term weight b^28 ~ 5.9e-7, negligible).
//   - KS step multipliers m1..m3 and carry scale b^(4*lane) hoisted per-lane.

constexpr int T_LEN = 4096;
constexpr int NT    = 16;            // tiles of 256 floats (64 lanes x float4)

__global__ __launch_bounds__(256) void ema_wavescan2_kernel(
    const float* __restrict__ x,
    const float* __restrict__ h0,
    float* __restrict__ out,
    int nseq)
{
    const int gtid = blockIdx.x * blockDim.x + threadIdx.x;
    const int wave = gtid >> 6;      // one wave per sequence
    const int lane = threadIdx.x & 63;
    if (wave >= nseq) return;

    const float a   = 0.4f;
    const float b   = 0.6f;
    const float b2  = b * b;
    const float b3  = b2 * b;
    const float b4  = b2 * b2;
    const float b8  = b4 * b4;
    const float b16 = b8 * b8;
    const float inv_b4 = 1.0f / b4;

    // Kogge-Stone step multipliers (0 for lanes with no source at distance d).
    const float m1 = (lane >= 1) ? b4  : 0.0f;
    const float m2 = (lane >= 2) ? b8  : 0.0f;
    const float m3 = (lane >= 4) ? b16 : 0.0f;
    // b^(4*lane): carry-in scale; underflow to 0 beyond lane ~20 = truncation.
    const float pb4i = exp2f((float)(4 * lane) * -0.73696559416f);

    const float4* __restrict__ xp = (const float4*)(x + (size_t)wave * T_LEN);
    float4* __restrict__ op       = (float4*)(out + (size_t)wave * T_LEN);

    // Phase 1: issue all 16 tile loads (independent, 16 KiB/wave in flight).
    float4 v[NT];
    #pragma unroll
    for (int it = 0; it < NT; ++it) v[it] = xp[it * 64 + lane];

    float h_in = h0[wave];           // true initial hidden state

    // Phase 2: scan + store, consuming loads in order.
    #pragma unroll
    for (int it = 0; it < NT; ++it) {
        float4 w = v[it];

        // Lane-local inclusive scan (zero-init): c_j = a*x_j + b*c_{j-1}
        float c0 = a * w.x;
        float c1 = fmaf(b, c0, a * w.y);
        float c2 = fmaf(b, c1, a * w.z);
        float c3 = fmaf(b, c2, a * w.w);

        // Kogge-Stone over lane tails; distance k carries weight b^(4k),
        // truncated beyond b^28 (~6e-7).
        float t = c3, u;
        u = __shfl_up(t, 1, 64); t = fmaf(m1, u, t);
        u = __shfl_up(t, 2, 64); t = fmaf(m2, u, t);
        u = __shfl_up(t, 4, 64); t = fmaf(m3, u, t);

        // Exclusive tail (algebraic, no 4th shuffle) + incoming tile carry.
        float e = fmaf(pb4i, h_in, (t - c3) * inv_b4);

        float4 o;
        o.x = fmaf(b , e, c0);
        o.y = fmaf(b2, e, c1);
        o.z = fmaf(b3, e, c2);
        o.w = fmaf(b4, e, c3);
        op[it * 64 + lane] = o;

        // Carry to next tile: scanned tail of lane 63.
        h_in = __shfl(t, 63, 64);
    }
}

extern "C" void kernel_launch(void* const* d_in, const int* in_sizes, int n_in,
                              void* d_out, int out_size, void* d_ws, size_t ws_size,
                              hipStream_t stream) {
    const float* x  = (const float*)d_in[0];   // [8,1024,4096] fp32
    const float* h0 = (const float*)d_in[1];   // [8,1024,1]    fp32
    float* out = (float*)d_out;                // [8,1024,4096] fp32

    const int nseq = in_sizes[1];              // 8192 sequences
    const int block = 256;                     // 4 waves -> 4 sequences/block
    const int grid = (nseq * 64 + block - 1) / block;  // 2048 blocks

    ema_wavescan2_kernel<<<grid, block, 0, stream>>>(x, h0, out, nseq);
}

// Round 5
// 221.024 us; speedup vs baseline: 1.3103x; 1.0456x over previous
//
#include <hip/hip_runtime.h>

// EMA recurrence: out[t] = a*x[t] + (1-a)*out[t-1] over T=4096 (contiguous),
// 8192 independent sequences [B=8, D=1024, T=4096] fp32.
//
// R5 = R4 resubmit (R4 core-dumped with no counters; audit found no OOB --
// suspected infra flake) with hardened size_t indexing on every global
// access and a clamped warm-up address.
//
// Design: one wave per 256-float tile, ZERO inter-tile dependency.
//   - 131072 independent waves. Each: coalesced 64xfloat4 tile load +
//     lanes 0-7 load the preceding 8 float4 (warm-up, mostly L2-hit),
//     lane-local scan + 2 Kogge-Stone chains (3 shuffles each), 1 broadcast,
//     coalesced float4 store, exit. Latency hidden by wave churn
//     (fillBuffer-shaped), not in-wave pipelining -- R3 showed the compiler
//     sinks register preloads, capping in-wave MLP at ~2 loads.
//   - Decay truncation: history older than 32 elements carries weight
//     0.6^32 ~ 8.4e-8 (threshold 5.5e-2). Warm-up scan from h=0 over the
//     previous 32 floats replaces the sequential carry. Tile 0 of each
//     sequence uses the true hidden init.

constexpr int TILES_PER_SEQ = 16;    // 4096 / 256

__global__ __launch_bounds__(256) void ema_tile_kernel(
    const float* __restrict__ x,
    const float* __restrict__ h0,
    float* __restrict__ out,
    int ntiles)
{
    const int gtid = blockIdx.x * blockDim.x + threadIdx.x;
    const int w    = gtid >> 6;      // global tile index = wave index
    const int lane = threadIdx.x & 63;
    if (w >= ntiles) return;

    const int tidx = w & (TILES_PER_SEQ - 1);
    const int seq  = w >> 4;

    const float a   = 0.4f;
    const float b   = 0.6f;
    const float b2  = b * b;
    const float b3  = b2 * b;
    const float b4  = b2 * b2;
    const float b8  = b4 * b4;
    const float b16 = b8 * b8;
    const float inv_b4 = 1.0f / b4;

    // Kogge-Stone step multipliers (0 where no source at that distance).
    const float m1 = (lane >= 1) ? b4  : 0.0f;
    const float m2 = (lane >= 2) ? b8  : 0.0f;
    const float m3 = (lane >= 4) ? b16 : 0.0f;
    // b^(4*lane): carry-in scale; underflows to 0 beyond lane ~20 (truncation).
    const float pb4i = exp2f((float)(4 * lane) * -0.73696559416f);

    const float4* __restrict__ xp = (const float4*)x;
    float4* __restrict__ op       = (float4*)out;

    // All flat indices in size_t BEFORE pointer arithmetic.
    const size_t tile_base = (size_t)w * 64;

    // Main tile load: lane i gets floats [w*256 + 4i, ...+4). Fully coalesced.
    float4 v = xp[tile_base + (size_t)lane];

    // Warm-up load: previous 32 floats, lanes 0-7 (wave-uniform branch).
    const bool has_warm = (tidx != 0);
    float4 wv = make_float4(0.f, 0.f, 0.f, 0.f);
    if (has_warm && lane < 8) {
        wv = xp[tile_base - 8 + (size_t)lane];   // tile_base >= 64 here
    }

    // --- main lane-local scan (zero-init): c_j = a*x_j + b*c_{j-1} ---
    float c0 = a * v.x;
    float c1 = fmaf(b, c0, a * v.y);
    float c2 = fmaf(b, c1, a * v.z);
    float c3 = fmaf(b, c2, a * v.w);

    // KS over lane tails (distance k weight b^(4k), truncated at b^32).
    float t = c3, u;
    u = __shfl_up(t, 1, 64); t = fmaf(m1, u, t);
    u = __shfl_up(t, 2, 64); t = fmaf(m2, u, t);
    u = __shfl_up(t, 4, 64); t = fmaf(m3, u, t);

    // --- incoming state h_in at tile start ---
    float h_in;
    if (has_warm) {
        // Scan the 32 warm-up floats (lanes 0-7) from h=0; take lane 7's tail.
        float d0 = a * wv.x;
        float d1 = fmaf(b, d0, a * wv.y);
        float d2 = fmaf(b, d1, a * wv.z);
        float d3 = fmaf(b, d2, a * wv.w);
        float tw = d3;
        u = __shfl_up(tw, 1, 64); tw = fmaf(m1, u, tw);
        u = __shfl_up(tw, 2, 64); tw = fmaf(m2, u, tw);
        u = __shfl_up(tw, 4, 64); tw = fmaf(m3, u, tw);
        h_in = __shfl(tw, 7, 64);
    } else {
        h_in = h0[(size_t)seq];      // true initial hidden state (wave-uniform)
    }

    // Exclusive tail recovered algebraically (dropped term <= b^28 ~ 6e-7).
    float e = fmaf(pb4i, h_in, (t - c3) * inv_b4);

    float4 o;
    o.x = fmaf(b , e, c0);
    o.y = fmaf(b2, e, c1);
    o.z = fmaf(b3, e, c2);
    o.w = fmaf(b4, e, c3);
    op[tile_base + (size_t)lane] = o;
}

extern "C" void kernel_launch(void* const* d_in, const int* in_sizes, int n_in,
                              void* d_out, int out_size, void* d_ws, size_t ws_size,
                              hipStream_t stream) {
    const float* x  = (const float*)d_in[0];   // [8,1024,4096] fp32
    const float* h0 = (const float*)d_in[1];   // [8,1024,1]    fp32
    float* out = (float*)d_out;                // [8,1024,4096] fp32

    const int nseq   = in_sizes[1];            // 8192 sequences
    const int ntiles = nseq * TILES_PER_SEQ;   // 131072 waves
    const int block  = 256;                    // 4 waves/block
    const long long total = (long long)ntiles * 64;
    const int grid = (int)((total + block - 1) / block);  // 32768 blocks

    ema_tile_kernel<<<grid, block, 0, stream>>>(x, h0, out, ntiles);
}